// Round 10
// baseline (5999.585 us; speedup 1.0000x reference)
//
#include <hip/hip_runtime.h>
#include <math.h>

// ---------------------------------------------------------------------------
// SRRNN: state-regularized GRU.  B=64, S=512, I=256, H=512, K=256, TEMP=1.
//
// Round 10: R9 sync structure (proven: 16 groups x 16 CUs, 1 barrier/step,
// register-resident weight slices, agent-scope scalars) + LDS conflict fixes:
//  - x/p in chunked [4][16][20] layout: GEMM reads 2-way (free) instead of
//    8-way flat-stride; staging + softmax write chunked (R5-proven pattern).
//  - Dist vectorized: float4 s_T reads over k (conflict-free), j-halves
//    combined via shfl_xor(1).
//  - h_new: float4 p-chunks (broadcast) x scalar s_sl reads (2-way, free).
// ---------------------------------------------------------------------------

#define B_ 64
#define S_ 512
#define I_ 256
#define H_ 512
#define K_ 256
#define G3H 1536
#define NGRP 16
#define GCU 16
#define NB 4
#define DPC 32     // dims per CU
#define TPB 512
#define SPIN_MAX (1 << 14)

// workspace layout (bytes)
#define WS_FLAGS 0
#define WS_FLAGS_SZ (NGRP * GCU * 4)                   // 1024
#define WS_SWT 4096
#define WS_SWT_SZ (G3H * K_ * 4)
#define WS_GH0 (WS_SWT + WS_SWT_SZ)
#define WS_GH0_SZ (B_ * G3H * 4)
#define WS_PART (WS_GH0 + WS_GH0_SZ)
#define WS_PART_SZ (2 * NGRP * GCU * NB * K_ * 4)      // 2097152

// LDS float offsets
#define L_ST 0               // s_T[32][256]   j-major
#define L_SSL 8192           // s_sl[256][36]  k-major
#define L_XCH 17408          // x_ch [4][16][20]
#define L_PCH 18688          // p_ch [4][16][20]
#define L_GI 19968           // gi_sl [4][96]
#define L_GH 20352           // gh_sl [4][96]
#define L_HC 20736           // hc_sl [4][32]
#define L_HP 20864           // hp_sl [4][32]
#define L_BIH 20992          // [96]
#define L_BHH 21088          // [96]
#define L_D 21184            // d_sl [4][256]
#define SMEM_BYTES 90112     // 22208 floats = 88832B; >80KB -> 1 block/CU

#define OUT_OFF_HN (B_ * S_ * H_)
#define OUT_OFF_P (OUT_OFF_HN + B_ * H_)

#define AGENT __HIP_MEMORY_SCOPE_AGENT
#define RLX __ATOMIC_RELAXED

// ---------------------------------------------------------------------------
__global__ void kernel_swt(const float* __restrict__ Whh,
                           const float* __restrict__ states,
                           float* __restrict__ SWT) {
  int r0 = blockIdx.x * 8;
  int k = threadIdx.x;  // 0..255
  const float* sr = states + (size_t)k * H_;
  float acc[8];
#pragma unroll
  for (int q = 0; q < 8; ++q) acc[q] = 0.f;
  for (int j = 0; j < H_; ++j) {
    float sv = sr[j];
#pragma unroll
    for (int q = 0; q < 8; ++q) acc[q] += Whh[(size_t)(r0 + q) * H_ + j] * sv;
  }
#pragma unroll
  for (int q = 0; q < 8; ++q) SWT[(size_t)(r0 + q) * K_ + k] = acc[q];
}

__global__ void kernel_gh0(const float* __restrict__ Whh,
                           const float* __restrict__ h0,
                           float* __restrict__ Gh0) {
  int b = blockIdx.x;
  int tid = threadIdx.x;  // 256
  __shared__ float h[H_];
  for (int e = tid; e < H_; e += 256) h[e] = h0[(size_t)b * H_ + e];
  __syncthreads();
  for (int r = tid; r < G3H; r += 256) {
    const float* wr = Whh + (size_t)r * H_;
    float acc = 0.f;
    for (int j = 0; j < H_; ++j) acc += wr[j] * h[j];
    Gh0[(size_t)b * G3H + r] = acc;
  }
}

// ---------------------------------------------------------------------------
__device__ __forceinline__ float dot4(float4 a, float4 b) {
  return a.x * b.x + a.y * b.y + a.z * b.z + a.w * b.w;
}

__global__ __launch_bounds__(TPB, 2) void srrnn_main(
    const float* __restrict__ input, const float* __restrict__ h0,
    const float* __restrict__ W_ih, const float* __restrict__ bias_ih,
    const float* __restrict__ bias_hh, const float* __restrict__ states,
    const float* __restrict__ SWT, const float* __restrict__ Gh0,
    float* __restrict__ part, unsigned int* flags,
    float* __restrict__ out, float* __restrict__ hn,
    float* __restrict__ probs) {
  const int tid = threadIdx.x;
  const int g = blockIdx.x >> 4;   // group 0..15
  const int cu = blockIdx.x & 15;  // CU in group
  const int d0 = cu << 5;          // owned dim base (32 dims)
  unsigned* fl = flags + (g << 4);

  extern __shared__ float smem[];
  float* s_T = smem + L_ST;        // [j][256]
  float* s_sl = smem + L_SSL;      // [k][36]
  float* x_ch = smem + L_XCH;      // [4][16][20]
  float* p_ch = smem + L_PCH;      // [4][16][20]
  float* gi_sl = smem + L_GI;
  float* gh_sl = smem + L_GH;
  float* hc_sl = smem + L_HC;
  float* hp_sl = smem + L_HP;
  float* bih_sl = smem + L_BIH;
  float* bhh_sl = smem + L_BHH;
  float* d_sl = smem + L_D;

  const int wv = tid >> 6, lane = tid & 63;
  const int rowblk = tid >> 4, kseg = tid & 15;  // GEMM org: 32 rowblk x 16 kseg

  // ---- setup ----
  for (int e = tid; e < K_ * DPC; e += TPB) {
    int k = e >> 5, j = e & 31;
    float v = states[((size_t)k << 9) + d0 + j];
    s_T[j * 256 + k] = v;      // one-time conflicted write, amortized
    s_sl[k * 36 + j] = v;
  }
  if (tid < 96) {
    int grow = ((tid >> 5) << 9) + d0 + (tid & 31);
    bih_sl[tid] = bias_ih[grow];
    bhh_sl[tid] = bias_hh[grow];
  }
  if (tid < 128) {
    int b = tid >> 5, j = tid & 31;
    hp_sl[(b << 5) + j] = h0[((size_t)(g * NB + b) << 9) + d0 + j];
  }
  if (tid < 384) {
    int b = tid / 96, r = tid % 96;
    int grow = ((r >> 5) << 9) + d0 + (r & 31);
    gh_sl[b * 96 + r] = Gh0[(size_t)(g * NB + b) * G3H + grow];
  }
  // weight fragments -> registers: 3 rows x 16 k per thread, both matrices
  float4 wi[3][4], wh[3][4];
#pragma unroll
  for (int i = 0; i < 3; ++i) {
    int r = rowblk * 3 + i;  // 0..95
    int grow = ((r >> 5) << 9) + d0 + (r & 31);
    const float4* si = (const float4*)(W_ih + (size_t)grow * K_ + (kseg << 4));
    const float4* sh = (const float4*)(SWT + (size_t)grow * K_ + (kseg << 4));
    wi[i][0] = si[0]; wi[i][1] = si[1]; wi[i][2] = si[2]; wi[i][3] = si[3];
    wh[i][0] = sh[0]; wh[i][1] = sh[1]; wh[i][2] = sh[2]; wh[i][3] = sh[3];
  }
  __syncthreads();

  // ---- pre-loop: stage x(0) chunked, gi(0) ----
  if (tid < 256) {
    int b = tid >> 6, c = tid & 63;
    float4 v = *((const float4*)(input + ((size_t)(g * NB + b) * S_) * I_) + c);
    *(float4*)(x_ch + (b * 16 + (c >> 2)) * 20 + ((c & 3) << 2)) = v;
  }
  __syncthreads();
  {
    float acc[4][3] = {};
#pragma unroll
    for (int b = 0; b < 4; ++b) {
      const float4* xp = (const float4*)(x_ch + (b * 16 + kseg) * 20);
#pragma unroll
      for (int c = 0; c < 4; ++c) {
        float4 xv = xp[c];
#pragma unroll
        for (int i = 0; i < 3; ++i) acc[b][i] += dot4(wi[i][c], xv);
      }
    }
#pragma unroll
    for (int b = 0; b < 4; ++b)
#pragma unroll
      for (int i = 0; i < 3; ++i) {
        float v = acc[b][i];
        v += __shfl_xor(v, 1); v += __shfl_xor(v, 2);
        v += __shfl_xor(v, 4); v += __shfl_xor(v, 8);
        acc[b][i] = v;
      }
    if (kseg == 0) {
#pragma unroll
      for (int b = 0; b < 4; ++b)
#pragma unroll
        for (int i = 0; i < 3; ++i) gi_sl[b * 96 + rowblk * 3 + i] = acc[b][i];
    }
  }
  __syncthreads();

  for (int t = 0; t < S_; ++t) {
    const int slot = t & 1;
    float* pslot = part + ((size_t)(slot * NGRP + g) << 14);  // [16][4][256]

    // ---- A: gates + h_cand over owned 32 dims ----
    if (tid < 128) {
      int b = tid >> 5, j = tid & 31;
      float gir = gi_sl[b * 96 + j] + bih_sl[j];
      float giz = gi_sl[b * 96 + 32 + j] + bih_sl[32 + j];
      float gin = gi_sl[b * 96 + 64 + j] + bih_sl[64 + j];
      float ghr = gh_sl[b * 96 + j] + bhh_sl[j];
      float ghz = gh_sl[b * 96 + 32 + j] + bhh_sl[32 + j];
      float ghn = gh_sl[b * 96 + 64 + j] + bhh_sl[64 + j];
      float r = 1.f / (1.f + expf(-(gir + ghr)));
      float z = 1.f / (1.f + expf(-(giz + ghz)));
      float n = tanhf(gin + r * ghn);
      hc_sl[(b << 5) + j] = (1.f - z) * n + z * hp_sl[(b << 5) + j];
    }
    __syncthreads();

    // ---- B: dist partials, vectorized. thread = (b, k4, jh) ----
    {
      int b = tid >> 7;              // 0..3
      int sub = tid & 127;
      int k4 = sub >> 1;             // float4-of-k index 0..63
      int jh = sub & 1;              // j-half
      const float* hb = hc_sl + (b << 5) + (jh << 4);
      const float4* sp = (const float4*)(s_T + ((jh << 4) * 256) + (k4 << 2));
      float ax = 0.f, ay = 0.f, az = 0.f, aw = 0.f;
#pragma unroll
      for (int jj = 0; jj < 16; ++jj) {
        float4 s4 = sp[jj * 64];     // s_T[(jh*16+jj)][4*k4..]
        float hv = hb[jj];
        float e;
        e = hv - s4.x; ax += e * e;
        e = hv - s4.y; ay += e * e;
        e = hv - s4.z; az += e * e;
        e = hv - s4.w; aw += e * e;
      }
      ax += __shfl_xor(ax, 1);
      ay += __shfl_xor(ay, 1);
      az += __shfl_xor(az, 1);
      aw += __shfl_xor(aw, 1);
      if (jh == 0) {
        float* dpb = pslot + (cu << 10) + (b << 8) + (k4 << 2);
        __hip_atomic_store(dpb + 0, ax, RLX, AGENT);
        __hip_atomic_store(dpb + 1, ay, RLX, AGENT);
        __hip_atomic_store(dpb + 2, az, RLX, AGENT);
        __hip_atomic_store(dpb + 3, aw, RLX, AGENT);
      }
    }
    __syncthreads();  // drains vmcnt in all waves before release
    if (tid == 0)
      __hip_atomic_store(fl + cu, (unsigned)(t + 1), __ATOMIC_RELEASE, AGENT);

    // ---- C (barrier shadow): stage x(t+1) + gi(t+1) GEMM (register W_ih) ----
    if (t + 1 < S_) {
      if (tid < 256) {
        int b = tid >> 6, c = tid & 63;
        float4 v = *((const float4*)(input +
                     ((size_t)(g * NB + b) * S_ + (t + 1)) * I_) + c);
        *(float4*)(x_ch + (b * 16 + (c >> 2)) * 20 + ((c & 3) << 2)) = v;
      }
      __syncthreads();
      {
        float acc[4][3] = {};
#pragma unroll
        for (int b = 0; b < 4; ++b) {
          const float4* xp = (const float4*)(x_ch + (b * 16 + kseg) * 20);
#pragma unroll
          for (int c = 0; c < 4; ++c) {
            float4 xv = xp[c];
#pragma unroll
            for (int i = 0; i < 3; ++i) acc[b][i] += dot4(wi[i][c], xv);
          }
        }
#pragma unroll
        for (int b = 0; b < 4; ++b)
#pragma unroll
          for (int i = 0; i < 3; ++i) {
            float v = acc[b][i];
            v += __shfl_xor(v, 1); v += __shfl_xor(v, 2);
            v += __shfl_xor(v, 4); v += __shfl_xor(v, 8);
            acc[b][i] = v;
          }
        if (kseg == 0) {
#pragma unroll
          for (int b = 0; b < 4; ++b)
#pragma unroll
            for (int i = 0; i < 3; ++i)
              gi_sl[b * 96 + rowblk * 3 + i] = acc[b][i];
        }
      }
    }

    // ---- E: poll the 16 flags ----
    if (tid < GCU) {
      for (int it = 0; it < SPIN_MAX; ++it) {
        if (__hip_atomic_load(fl + tid, RLX, AGENT) >= (unsigned)(t + 1)) break;
        __builtin_amdgcn_s_sleep(1);
      }
    }
    __syncthreads();

    // ---- F: gather 16 partials (coalesced rows), sum -> d_sl ----
    {
      int bp = tid >> 8, k = tid & 255;
      int b1 = bp << 1, b2 = b1 + 1;
      const float* q1 = pslot + (b1 << 8) + k;
      const float* q2 = pslot + (b2 << 8) + k;
      float s1 = 0.f, s2 = 0.f;
#pragma unroll
      for (int c = 0; c < GCU; ++c) {
        s1 += __hip_atomic_load(q1 + (c << 10), RLX, AGENT);
        s2 += __hip_atomic_load(q2 + (c << 10), RLX, AGENT);
      }
      d_sl[(b1 << 8) + k] = s1;
      d_sl[(b2 << 8) + k] = s2;
    }
    __syncthreads();

    // ---- G: softmax (waves 0-3, wave = batch) -> p_ch chunked + probs ----
    if (wv < NB) {
      int b = wv;
      const float* db = d_sl + (b << 8);
      float dd0 = db[lane], dd1 = db[lane + 64], dd2 = db[lane + 128],
            dd3 = db[lane + 192];
      float mn = fminf(fminf(dd0, dd1), fminf(dd2, dd3));
#pragma unroll
      for (int off = 32; off >= 1; off >>= 1) mn = fminf(mn, __shfl_xor(mn, off));
      float e0 = expf(mn - dd0), e1 = expf(mn - dd1), e2 = expf(mn - dd2),
            e3 = expf(mn - dd3);
      float s = (e0 + e1) + (e2 + e3);
#pragma unroll
      for (int off = 32; off >= 1; off >>= 1) s += __shfl_xor(s, off);
      float inv = 1.f / s;
      e0 *= inv; e1 *= inv; e2 *= inv; e3 *= inv;
      int hi = lane >> 4, lo = lane & 15;
      p_ch[(b * 16 + hi + 0) * 20 + lo] = e0;
      p_ch[(b * 16 + hi + 4) * 20 + lo] = e1;
      p_ch[(b * 16 + hi + 8) * 20 + lo] = e2;
      p_ch[(b * 16 + hi + 12) * 20 + lo] = e3;
      if (cu == 0) {
        float* pr = probs + (((size_t)(g * NB + b) * S_ + t) << 8);
        pr[lane] = e0; pr[lane + 64] = e1; pr[lane + 128] = e2; pr[lane + 192] = e3;
      }
    }
    __syncthreads();

    // ---- H1: gh(t+1) = p @ SWT^T from registers; p from chunked layout ----
    if (t + 1 < S_) {
      float acc[4][3] = {};
#pragma unroll
      for (int b = 0; b < 4; ++b) {
        const float4* xp = (const float4*)(p_ch + (b * 16 + kseg) * 20);
#pragma unroll
        for (int c = 0; c < 4; ++c) {
          float4 xv = xp[c];
#pragma unroll
          for (int i = 0; i < 3; ++i) acc[b][i] += dot4(wh[i][c], xv);
        }
      }
#pragma unroll
      for (int b = 0; b < 4; ++b)
#pragma unroll
        for (int i = 0; i < 3; ++i) {
          float v = acc[b][i];
          v += __shfl_xor(v, 1); v += __shfl_xor(v, 2);
          v += __shfl_xor(v, 4); v += __shfl_xor(v, 8);
          acc[b][i] = v;
        }
      if (kseg == 0) {
#pragma unroll
        for (int b = 0; b < 4; ++b)
#pragma unroll
          for (int i = 0; i < 3; ++i)
            gh_sl[b * 96 + rowblk * 3 + i] = acc[b][i];
      }
    }

    // ---- H2: h_new. thread = (b, j, kq); float4 p-chunks, scalar s_sl ----
    {
      int b = tid >> 7, j = (tid >> 2) & 31, kq = tid & 3;
      float a = 0.f;
#pragma unroll
      for (int i = 0; i < 16; ++i) {
        float4 p4 = *(const float4*)(p_ch + (b * 16 + i) * 20 + (kq << 2));
        int k = (i << 4) + (kq << 2);
        a += p4.x * s_sl[(k + 0) * 36 + j] + p4.y * s_sl[(k + 1) * 36 + j] +
             p4.z * s_sl[(k + 2) * 36 + j] + p4.w * s_sl[(k + 3) * 36 + j];
      }
      a += __shfl_xor(a, 1);
      a += __shfl_xor(a, 2);
      if (kq == 0) {
        hp_sl[(b << 5) + j] = a;
        out[(((size_t)(g * NB + b) * S_ + t) << 9) + d0 + j] = a;
      }
    }
    __syncthreads();
  }

  // ---- final hidden state ----
  if (tid < 128) {
    int b = tid >> 5, j = tid & 31;
    hn[((size_t)(g * NB + b) << 9) + d0 + j] = hp_sl[(b << 5) + j];
  }
}

// ---------------------------------------------------------------------------
extern "C" void kernel_launch(void* const* d_in, const int* in_sizes, int n_in,
                              void* d_out, int out_size, void* d_ws,
                              size_t ws_size, hipStream_t stream) {
  const float* input = (const float*)d_in[0];
  const float* h0 = (const float*)d_in[1];
  const float* W_ih = (const float*)d_in[2];
  const float* W_hh = (const float*)d_in[3];
  const float* bias_ih = (const float*)d_in[4];
  const float* bias_hh = (const float*)d_in[5];
  const float* states = (const float*)d_in[6];
  float* out = (float*)d_out;

  char* ws = (char*)d_ws;
  unsigned int* flags = (unsigned int*)(ws + WS_FLAGS);
  float* SWT = (float*)(ws + WS_SWT);
  float* Gh0 = (float*)(ws + WS_GH0);
  float* part = (float*)(ws + WS_PART);

  (void)hipMemsetAsync(d_ws, 0, WS_FLAGS_SZ, stream);  // flags -> 0
  kernel_swt<<<G3H / 8, 256, 0, stream>>>(W_hh, states, SWT);
  kernel_gh0<<<B_, 256, 0, stream>>>(W_hh, h0, Gh0);

  (void)hipFuncSetAttribute(reinterpret_cast<const void*>(srrnn_main),
                            hipFuncAttributeMaxDynamicSharedMemorySize,
                            SMEM_BYTES);
  srrnn_main<<<NGRP * GCU, TPB, SMEM_BYTES, stream>>>(
      input, h0, W_ih, bias_ih, bias_hh, states, SWT, Gh0, part, flags,
      out, out + OUT_OFF_HN, out + OUT_OFF_P);
}

// Round 11
// 4875.987 us; speedup vs baseline: 1.2304x; 1.2304x over previous
//
#include <hip/hip_runtime.h>
#include <math.h>

// ---------------------------------------------------------------------------
// SRRNN: state-regularized GRU.  B=64, S=512, I=256, H=512, K=256, TEMP=1.
//
// Round 11: tag-carried data + reducer-per-batch (no flags, no barriers).
//  - Every cross-CU word is a 64-bit atomic (tag<<32)|float_bits. Consumers
//    poll the word itself: tag observation == data observation (1 MALL trip).
//    Single-slot ABA-safe: tags strictly increase; producer t+2 write is
//    program-ordered after consuming t+1 (which required all consumers done
//    with t). Buffers memset(0) per launch -> no cross-replay tag collision.
//  - CU b (b<4) is the reducer for batch b: polls 16 partials (32KB), d-sum,
//    softmax, publishes tagged p (2KB) + probs. Workers poll only p (8KB).
//    Gather volume 16 MB/step -> 4 MB/step.
//  - Workers do x(t+1)+gi(t+1) shadow while reducers reduce (latency hidden);
//    reducers do their shadow after publishing p.
//  - Compute kernels (gates/dist/GEMMs/h_new) and LDS layouts = R10 (proven).
// ---------------------------------------------------------------------------

#define B_ 64
#define S_ 512
#define I_ 256
#define H_ 512
#define K_ 256
#define G3H 1536
#define NGRP 16
#define GCU 16
#define NB 4
#define DPC 32     // dims per CU
#define TPB 512
#define SPIN_MAX (1 << 15)

// workspace layout (bytes)
#define WS_SWT 4096
#define WS_SWT_SZ (G3H * K_ * 4)                       // 1572864
#define WS_GH0 (WS_SWT + WS_SWT_SZ)
#define WS_GH0_SZ (B_ * G3H * 4)                       // 393216
#define WS_PARTT (WS_GH0 + WS_GH0_SZ)                  // 1970176 (8B aligned)
#define WS_PARTT_SZ (NGRP * NB * GCU * K_ * 8)         // 2097152
#define WS_PB (WS_PARTT + WS_PARTT_SZ)
#define WS_PB_SZ (NGRP * NB * K_ * 8)                  // 131072
#define WS_TAG_MEMSET_SZ (WS_PARTT_SZ + WS_PB_SZ)      // 2228224

// LDS float offsets (R10 map)
#define L_ST 0               // s_T[32][256]   j-major
#define L_SSL 8192           // s_sl[256][36]  k-major
#define L_XCH 17408          // x_ch [4][16][20]
#define L_PCH 18688          // p_ch [4][16][20]
#define L_GI 19968           // gi_sl [4][96]
#define L_GH 20352           // gh_sl [4][96]
#define L_HC 20736           // hc_sl [4][32]
#define L_HP 20864           // hp_sl [4][32]
#define L_BIH 20992          // [96]
#define L_BHH 21088          // [96]
#define L_D 21184            // d_sl [256] (reducer only)
#define SMEM_BYTES 90112     // >80KB -> 1 block/CU

#define OUT_OFF_HN (B_ * S_ * H_)
#define OUT_OFF_P (OUT_OFF_HN + B_ * H_)

#define AGENT __HIP_MEMORY_SCOPE_AGENT
#define RLX __ATOMIC_RELAXED

// ---------------------------------------------------------------------------
__global__ void kernel_swt(const float* __restrict__ Whh,
                           const float* __restrict__ states,
                           float* __restrict__ SWT) {
  int r0 = blockIdx.x * 8;
  int k = threadIdx.x;  // 0..255
  const float* sr = states + (size_t)k * H_;
  float acc[8];
#pragma unroll
  for (int q = 0; q < 8; ++q) acc[q] = 0.f;
  for (int j = 0; j < H_; ++j) {
    float sv = sr[j];
#pragma unroll
    for (int q = 0; q < 8; ++q) acc[q] += Whh[(size_t)(r0 + q) * H_ + j] * sv;
  }
#pragma unroll
  for (int q = 0; q < 8; ++q) SWT[(size_t)(r0 + q) * K_ + k] = acc[q];
}

__global__ void kernel_gh0(const float* __restrict__ Whh,
                           const float* __restrict__ h0,
                           float* __restrict__ Gh0) {
  int b = blockIdx.x;
  int tid = threadIdx.x;  // 256
  __shared__ float h[H_];
  for (int e = tid; e < H_; e += 256) h[e] = h0[(size_t)b * H_ + e];
  __syncthreads();
  for (int r = tid; r < G3H; r += 256) {
    const float* wr = Whh + (size_t)r * H_;
    float acc = 0.f;
    for (int j = 0; j < H_; ++j) acc += wr[j] * h[j];
    Gh0[(size_t)b * G3H + r] = acc;
  }
}

// ---------------------------------------------------------------------------
__device__ __forceinline__ float dot4(float4 a, float4 b) {
  return a.x * b.x + a.y * b.y + a.z * b.z + a.w * b.w;
}
__device__ __forceinline__ void tstore(unsigned long long* p, unsigned tau,
                                       float v) {
  unsigned long long w =
      ((unsigned long long)tau << 32) | (unsigned long long)__float_as_uint(v);
  __hip_atomic_store(p, w, RLX, AGENT);
}
__device__ __forceinline__ unsigned long long tload(
    const unsigned long long* p) {
  return __hip_atomic_load(p, RLX, AGENT);
}

__global__ __launch_bounds__(TPB, 2) void srrnn_main(
    const float* __restrict__ input, const float* __restrict__ h0,
    const float* __restrict__ W_ih, const float* __restrict__ bias_ih,
    const float* __restrict__ bias_hh, const float* __restrict__ states,
    const float* __restrict__ SWT, const float* __restrict__ Gh0,
    unsigned long long* __restrict__ partt, unsigned long long* __restrict__ pb,
    float* __restrict__ out, float* __restrict__ hn,
    float* __restrict__ probs) {
  const int tid = threadIdx.x;
  const int g = blockIdx.x >> 4;   // group 0..15
  const int cu = blockIdx.x & 15;  // CU in group
  const int d0 = cu << 5;          // owned dim base (32 dims)

  extern __shared__ float smem[];
  float* s_T = smem + L_ST;        // [j][256]
  float* s_sl = smem + L_SSL;      // [k][36]
  float* x_ch = smem + L_XCH;      // [4][16][20]
  float* p_ch = smem + L_PCH;      // [4][16][20]
  float* gi_sl = smem + L_GI;
  float* gh_sl = smem + L_GH;
  float* hc_sl = smem + L_HC;
  float* hp_sl = smem + L_HP;
  float* bih_sl = smem + L_BIH;
  float* bhh_sl = smem + L_BHH;
  float* d_sl = smem + L_D;

  const int wv = tid >> 6, lane = tid & 63;
  const int rowblk = tid >> 4, kseg = tid & 15;  // GEMM org: 32 rowblk x 16 kseg

  // ---- setup ----
  for (int e = tid; e < K_ * DPC; e += TPB) {
    int k = e >> 5, j = e & 31;
    float v = states[((size_t)k << 9) + d0 + j];
    s_T[j * 256 + k] = v;
    s_sl[k * 36 + j] = v;
  }
  if (tid < 96) {
    int grow = ((tid >> 5) << 9) + d0 + (tid & 31);
    bih_sl[tid] = bias_ih[grow];
    bhh_sl[tid] = bias_hh[grow];
  }
  if (tid < 128) {
    int b = tid >> 5, j = tid & 31;
    hp_sl[(b << 5) + j] = h0[((size_t)(g * NB + b) << 9) + d0 + j];
  }
  if (tid < 384) {
    int b = tid / 96, r = tid % 96;
    int grow = ((r >> 5) << 9) + d0 + (r & 31);
    gh_sl[b * 96 + r] = Gh0[(size_t)(g * NB + b) * G3H + grow];
  }
  // weight fragments -> registers: 3 rows x 16 k per thread, both matrices
  float4 wi[3][4], wh[3][4];
#pragma unroll
  for (int i = 0; i < 3; ++i) {
    int r = rowblk * 3 + i;  // 0..95
    int grow = ((r >> 5) << 9) + d0 + (r & 31);
    const float4* si = (const float4*)(W_ih + (size_t)grow * K_ + (kseg << 4));
    const float4* sh = (const float4*)(SWT + (size_t)grow * K_ + (kseg << 4));
    wi[i][0] = si[0]; wi[i][1] = si[1]; wi[i][2] = si[2]; wi[i][3] = si[3];
    wh[i][0] = sh[0]; wh[i][1] = sh[1]; wh[i][2] = sh[2]; wh[i][3] = sh[3];
  }
  __syncthreads();

  // ---- pre-loop: stage x(0) chunked, gi(0) ----
  if (tid < 256) {
    int b = tid >> 6, c = tid & 63;
    float4 v = *((const float4*)(input + ((size_t)(g * NB + b) * S_) * I_) + c);
    *(float4*)(x_ch + (b * 16 + (c >> 2)) * 20 + ((c & 3) << 2)) = v;
  }
  __syncthreads();
  {
    float acc[4][3] = {};
#pragma unroll
    for (int b = 0; b < 4; ++b) {
      const float4* xp = (const float4*)(x_ch + (b * 16 + kseg) * 20);
#pragma unroll
      for (int c = 0; c < 4; ++c) {
        float4 xv = xp[c];
#pragma unroll
        for (int i = 0; i < 3; ++i) acc[b][i] += dot4(wi[i][c], xv);
      }
    }
#pragma unroll
    for (int b = 0; b < 4; ++b)
#pragma unroll
      for (int i = 0; i < 3; ++i) {
        float v = acc[b][i];
        v += __shfl_xor(v, 1); v += __shfl_xor(v, 2);
        v += __shfl_xor(v, 4); v += __shfl_xor(v, 8);
        acc[b][i] = v;
      }
    if (kseg == 0) {
#pragma unroll
      for (int b = 0; b < 4; ++b)
#pragma unroll
        for (int i = 0; i < 3; ++i) gi_sl[b * 96 + rowblk * 3 + i] = acc[b][i];
    }
  }
  __syncthreads();

  for (int t = 0; t < S_; ++t) {
    const unsigned tau = (unsigned)(t + 1);

    // ---- A: gates + h_cand over owned 32 dims ----
    if (tid < 128) {
      int b = tid >> 5, j = tid & 31;
      float gir = gi_sl[b * 96 + j] + bih_sl[j];
      float giz = gi_sl[b * 96 + 32 + j] + bih_sl[32 + j];
      float gin = gi_sl[b * 96 + 64 + j] + bih_sl[64 + j];
      float ghr = gh_sl[b * 96 + j] + bhh_sl[j];
      float ghz = gh_sl[b * 96 + 32 + j] + bhh_sl[32 + j];
      float ghn = gh_sl[b * 96 + 64 + j] + bhh_sl[64 + j];
      float r = 1.f / (1.f + expf(-(gir + ghr)));
      float z = 1.f / (1.f + expf(-(giz + ghz)));
      float n = tanhf(gin + r * ghn);
      hc_sl[(b << 5) + j] = (1.f - z) * n + z * hp_sl[(b << 5) + j];
    }
    __syncthreads();

    // ---- B: dist partials (R10 vectorized) -> TAGGED stores ----
    {
      int b = tid >> 7;              // 0..3
      int sub = tid & 127;
      int k4 = sub >> 1;             // float4-of-k index 0..63
      int jh = sub & 1;              // j-half
      const float* hb = hc_sl + (b << 5) + (jh << 4);
      const float4* sp = (const float4*)(s_T + ((jh << 4) * 256) + (k4 << 2));
      float ax = 0.f, ay = 0.f, az = 0.f, aw = 0.f;
#pragma unroll
      for (int jj = 0; jj < 16; ++jj) {
        float4 s4 = sp[jj * 64];
        float hv = hb[jj];
        float e;
        e = hv - s4.x; ax += e * e;
        e = hv - s4.y; ay += e * e;
        e = hv - s4.z; az += e * e;
        e = hv - s4.w; aw += e * e;
      }
      ax += __shfl_xor(ax, 1);
      ay += __shfl_xor(ay, 1);
      az += __shfl_xor(az, 1);
      aw += __shfl_xor(aw, 1);
      if (jh == 0) {
        unsigned long long* dpb =
            partt + ((((size_t)(g * NB + b) * GCU) + cu) << 8) + (k4 << 2);
        tstore(dpb + 0, tau, ax);
        tstore(dpb + 1, tau, ay);
        tstore(dpb + 2, tau, az);
        tstore(dpb + 3, tau, aw);
      }
    }

    // ---- R (reducers only, cu<4): poll 16 partials, d-sum, softmax, pub p --
    if (cu < NB) {
      {
        int k = tid >> 1, half = tid & 1;  // 8 srcs per thread
        const unsigned long long* base =
            partt + ((((size_t)(g * NB + cu) * GCU) + (half << 3)) << 8) + k;
        unsigned long long w[8];
#pragma unroll
        for (int s = 0; s < 8; ++s) w[s] = tload(base + (s << 8));
#pragma unroll
        for (int s = 0; s < 8; ++s) {
          int it = 0;
          while ((unsigned)(w[s] >> 32) != tau && ++it < SPIN_MAX)
            w[s] = tload(base + (s << 8));
        }
        float dsum = 0.f;
#pragma unroll
        for (int s = 0; s < 8; ++s)
          dsum += __uint_as_float((unsigned)(w[s] & 0xffffffffu));
        dsum += __shfl_xor(dsum, 1);
        if (half == 0) d_sl[k] = dsum;
      }
      __syncthreads();
      if (wv == 0) {
        float dd0 = d_sl[lane], dd1 = d_sl[lane + 64], dd2 = d_sl[lane + 128],
              dd3 = d_sl[lane + 192];
        float mn = fminf(fminf(dd0, dd1), fminf(dd2, dd3));
#pragma unroll
        for (int off = 32; off >= 1; off >>= 1)
          mn = fminf(mn, __shfl_xor(mn, off));
        float e0 = expf(mn - dd0), e1 = expf(mn - dd1), e2 = expf(mn - dd2),
              e3 = expf(mn - dd3);
        float s = (e0 + e1) + (e2 + e3);
#pragma unroll
        for (int off = 32; off >= 1; off >>= 1) s += __shfl_xor(s, off);
        float inv = 1.f / s;
        e0 *= inv; e1 *= inv; e2 *= inv; e3 *= inv;
        unsigned long long* pbw = pb + ((size_t)(g * NB + cu) << 8);
        tstore(pbw + lane, tau, e0);
        tstore(pbw + lane + 64, tau, e1);
        tstore(pbw + lane + 128, tau, e2);
        tstore(pbw + lane + 192, tau, e3);
        float* pr = probs + (((size_t)(g * NB + cu) * S_ + t) << 8);
        pr[lane] = e0; pr[lane + 64] = e1; pr[lane + 128] = e2;
        pr[lane + 192] = e3;
      }
    }

    // ---- C (shadow): stage x(t+1) + gi(t+1) GEMM (register W_ih) ----
    if (t + 1 < S_) {
      if (tid < 256) {
        int b = tid >> 6, c = tid & 63;
        float4 v = *((const float4*)(input +
                     ((size_t)(g * NB + b) * S_ + (t + 1)) * I_) + c);
        *(float4*)(x_ch + (b * 16 + (c >> 2)) * 20 + ((c & 3) << 2)) = v;
      }
      __syncthreads();
      {
        float acc[4][3] = {};
#pragma unroll
        for (int b = 0; b < 4; ++b) {
          const float4* xp = (const float4*)(x_ch + (b * 16 + kseg) * 20);
#pragma unroll
          for (int c = 0; c < 4; ++c) {
            float4 xv = xp[c];
#pragma unroll
            for (int i = 0; i < 3; ++i) acc[b][i] += dot4(wi[i][c], xv);
          }
        }
#pragma unroll
        for (int b = 0; b < 4; ++b)
#pragma unroll
          for (int i = 0; i < 3; ++i) {
            float v = acc[b][i];
            v += __shfl_xor(v, 1); v += __shfl_xor(v, 2);
            v += __shfl_xor(v, 4); v += __shfl_xor(v, 8);
            acc[b][i] = v;
          }
        if (kseg == 0) {
#pragma unroll
          for (int b = 0; b < 4; ++b)
#pragma unroll
            for (int i = 0; i < 3; ++i)
              gi_sl[b * 96 + rowblk * 3 + i] = acc[b][i];
        }
      }
    }

    // ---- P: poll tagged p (all 4 batches), fill p_ch chunked ----
    {
      const unsigned long long* pbg = pb + ((size_t)g << 10);
      unsigned long long w0 = tload(pbg + tid);
      unsigned long long w1 = tload(pbg + 512 + tid);
      int it = 0;
      while ((unsigned)(w0 >> 32) != tau && ++it < SPIN_MAX)
        w0 = tload(pbg + tid);
      it = 0;
      while ((unsigned)(w1 >> 32) != tau && ++it < SPIN_MAX)
        w1 = tload(pbg + 512 + tid);
      int b0 = tid >> 8, k0 = tid & 255;
      int b1 = 2 + b0, k1 = k0;
      p_ch[(b0 * 16 + (k0 >> 4)) * 20 + (k0 & 15)] =
          __uint_as_float((unsigned)(w0 & 0xffffffffu));
      p_ch[(b1 * 16 + (k1 >> 4)) * 20 + (k1 & 15)] =
          __uint_as_float((unsigned)(w1 & 0xffffffffu));
    }
    __syncthreads();

    // ---- H1: gh(t+1) = p @ SWT^T from registers; p from chunked layout ----
    if (t + 1 < S_) {
      float acc[4][3] = {};
#pragma unroll
      for (int b = 0; b < 4; ++b) {
        const float4* xp = (const float4*)(p_ch + (b * 16 + kseg) * 20);
#pragma unroll
        for (int c = 0; c < 4; ++c) {
          float4 xv = xp[c];
#pragma unroll
          for (int i = 0; i < 3; ++i) acc[b][i] += dot4(wh[i][c], xv);
        }
      }
#pragma unroll
      for (int b = 0; b < 4; ++b)
#pragma unroll
        for (int i = 0; i < 3; ++i) {
          float v = acc[b][i];
          v += __shfl_xor(v, 1); v += __shfl_xor(v, 2);
          v += __shfl_xor(v, 4); v += __shfl_xor(v, 8);
          acc[b][i] = v;
        }
      if (kseg == 0) {
#pragma unroll
        for (int b = 0; b < 4; ++b)
#pragma unroll
          for (int i = 0; i < 3; ++i)
            gh_sl[b * 96 + rowblk * 3 + i] = acc[b][i];
      }
    }

    // ---- H2: h_new (R10). thread = (b, j, kq) ----
    {
      int b = tid >> 7, j = (tid >> 2) & 31, kq = tid & 3;
      float a = 0.f;
#pragma unroll
      for (int i = 0; i < 16; ++i) {
        float4 p4 = *(const float4*)(p_ch + (b * 16 + i) * 20 + (kq << 2));
        int k = (i << 4) + (kq << 2);
        a += p4.x * s_sl[(k + 0) * 36 + j] + p4.y * s_sl[(k + 1) * 36 + j] +
             p4.z * s_sl[(k + 2) * 36 + j] + p4.w * s_sl[(k + 3) * 36 + j];
      }
      a += __shfl_xor(a, 1);
      a += __shfl_xor(a, 2);
      if (kq == 0) {
        hp_sl[(b << 5) + j] = a;
        out[(((size_t)(g * NB + b) * S_ + t) << 9) + d0 + j] = a;
      }
    }
    __syncthreads();
  }

  // ---- final hidden state ----
  if (tid < 128) {
    int b = tid >> 5, j = tid & 31;
    hn[((size_t)(g * NB + b) << 9) + d0 + j] = hp_sl[(b << 5) + j];
  }
}

// ---------------------------------------------------------------------------
extern "C" void kernel_launch(void* const* d_in, const int* in_sizes, int n_in,
                              void* d_out, int out_size, void* d_ws,
                              size_t ws_size, hipStream_t stream) {
  const float* input = (const float*)d_in[0];
  const float* h0 = (const float*)d_in[1];
  const float* W_ih = (const float*)d_in[2];
  const float* W_hh = (const float*)d_in[3];
  const float* bias_ih = (const float*)d_in[4];
  const float* bias_hh = (const float*)d_in[5];
  const float* states = (const float*)d_in[6];
  float* out = (float*)d_out;

  char* ws = (char*)d_ws;
  float* SWT = (float*)(ws + WS_SWT);
  float* Gh0 = (float*)(ws + WS_GH0);
  unsigned long long* partt = (unsigned long long*)(ws + WS_PARTT);
  unsigned long long* pb = (unsigned long long*)(ws + WS_PB);

  // zero all tagged buffers: tag 0 never matches tau in [1,512]; prevents
  // cross-replay stale-tag collisions (harness does not re-poison d_ws).
  (void)hipMemsetAsync(ws + WS_PARTT, 0, WS_TAG_MEMSET_SZ, stream);
  kernel_swt<<<G3H / 8, 256, 0, stream>>>(W_hh, states, SWT);
  kernel_gh0<<<B_, 256, 0, stream>>>(W_hh, h0, Gh0);

  (void)hipFuncSetAttribute(reinterpret_cast<const void*>(srrnn_main),
                            hipFuncAttributeMaxDynamicSharedMemorySize,
                            SMEM_BYTES);
  srrnn_main<<<NGRP * GCU, TPB, SMEM_BYTES, stream>>>(
      input, h0, W_ih, bias_ih, bias_hh, states, SWT, Gh0, partt, pb,
      out, out + OUT_OFF_HN, out + OUT_OFF_P);
}

// Round 12
// 4077.213 us; speedup vs baseline: 1.4715x; 1.1959x over previous
//
#include <hip/hip_runtime.h>
#include <math.h>

// ---------------------------------------------------------------------------
// SRRNN: state-regularized GRU.  B=64, S=512, I=256, H=512, K=256, TEMP=1.
//
// Round 12: ONE MALL hop per step.
//  - Full-replication reduce: every CU polls all 16 CUs' dist partials,
//    reduces + softmaxes locally (no reducer stage, no p-publish hop).
//  - Sign-bit validity protocol: all communicated values >= 0, so the sign
//    bit carries freshness. 2 slots (t&1), expected sign = (t>>1)&1, buffers
//    memset(0x80) per launch (stale = negative = never matches at t=0,1).
//    Writer at t overwrites t-2; any CU at t consumed all t-1 partials =>
//    every CU finished its t-2 poll (distance-2 self-sync). 2 f32 packed per
//    64-bit atomic word -> half the atomic count of R11, no tag words.
//  - Compute path (register weights, chunked LDS, gi shadow, gh/h_new) = R11.
// ---------------------------------------------------------------------------

#define B_ 64
#define S_ 512
#define I_ 256
#define H_ 512
#define K_ 256
#define G3H 1536
#define NGRP 16
#define GCU 16
#define NB 4
#define DPC 32     // dims per CU
#define TPB 512
#define SPIN_MAX (1 << 15)

// workspace layout (bytes)
#define WS_SWT 4096
#define WS_SWT_SZ (G3H * K_ * 4)                       // 1572864
#define WS_GH0 (WS_SWT + WS_SWT_SZ)
#define WS_GH0_SZ (B_ * G3H * 4)                       // 393216
#define WS_PK (WS_GH0 + WS_GH0_SZ)                     // 1970176 (8B aligned)
#define WS_PK_SZ (2 * NGRP * NB * GCU * 128 * 8)       // 2097152

// LDS float offsets (R10/R11 map)
#define L_ST 0               // s_T[32][256]   j-major
#define L_SSL 8192           // s_sl[256][36]  k-major
#define L_XCH 17408          // x_ch [4][16][20]
#define L_PCH 18688          // p_ch [4][16][20]
#define L_GI 19968           // gi_sl [4][96]
#define L_GH 20352           // gh_sl [4][96]
#define L_HC 20736           // hc_sl [4][32]
#define L_HP 20864           // hp_sl [4][32]
#define L_BIH 20992          // [96]
#define L_BHH 21088          // [96]
#define L_D 21184            // d_sl [4][256]
#define SMEM_BYTES 90112     // >80KB -> 1 block/CU

#define OUT_OFF_HN (B_ * S_ * H_)
#define OUT_OFF_P (OUT_OFF_HN + B_ * H_)

#define AGENT __HIP_MEMORY_SCOPE_AGENT
#define RLX __ATOMIC_RELAXED
#define SGNMASK 0x8000000080000000ull

// ---------------------------------------------------------------------------
__global__ void kernel_swt(const float* __restrict__ Whh,
                           const float* __restrict__ states,
                           float* __restrict__ SWT) {
  int r0 = blockIdx.x * 8;
  int k = threadIdx.x;  // 0..255
  const float* sr = states + (size_t)k * H_;
  float acc[8];
#pragma unroll
  for (int q = 0; q < 8; ++q) acc[q] = 0.f;
  for (int j = 0; j < H_; ++j) {
    float sv = sr[j];
#pragma unroll
    for (int q = 0; q < 8; ++q) acc[q] += Whh[(size_t)(r0 + q) * H_ + j] * sv;
  }
#pragma unroll
  for (int q = 0; q < 8; ++q) SWT[(size_t)(r0 + q) * K_ + k] = acc[q];
}

__global__ void kernel_gh0(const float* __restrict__ Whh,
                           const float* __restrict__ h0,
                           float* __restrict__ Gh0) {
  int b = blockIdx.x;
  int tid = threadIdx.x;  // 256
  __shared__ float h[H_];
  for (int e = tid; e < H_; e += 256) h[e] = h0[(size_t)b * H_ + e];
  __syncthreads();
  for (int r = tid; r < G3H; r += 256) {
    const float* wr = Whh + (size_t)r * H_;
    float acc = 0.f;
    for (int j = 0; j < H_; ++j) acc += wr[j] * h[j];
    Gh0[(size_t)b * G3H + r] = acc;
  }
}

// ---------------------------------------------------------------------------
__device__ __forceinline__ float dot4(float4 a, float4 b) {
  return a.x * b.x + a.y * b.y + a.z * b.z + a.w * b.w;
}
__device__ __forceinline__ unsigned long long pk_pack(float lo, float hi,
                                                      unsigned sb) {
  return ((unsigned long long)(__float_as_uint(hi) | sb) << 32) |
         (unsigned long long)(__float_as_uint(lo) | sb);
}
__device__ __forceinline__ unsigned long long tload(
    const unsigned long long* p) {
  return __hip_atomic_load(p, RLX, AGENT);
}
__device__ __forceinline__ void tstore(unsigned long long* p,
                                       unsigned long long w) {
  __hip_atomic_store(p, w, RLX, AGENT);
}

__global__ __launch_bounds__(TPB, 2) void srrnn_main(
    const float* __restrict__ input, const float* __restrict__ h0,
    const float* __restrict__ W_ih, const float* __restrict__ bias_ih,
    const float* __restrict__ bias_hh, const float* __restrict__ states,
    const float* __restrict__ SWT, const float* __restrict__ Gh0,
    unsigned long long* __restrict__ pk,
    float* __restrict__ out, float* __restrict__ hn,
    float* __restrict__ probs) {
  const int tid = threadIdx.x;
  const int g = blockIdx.x >> 4;   // group 0..15
  const int cu = blockIdx.x & 15;  // CU in group
  const int d0 = cu << 5;          // owned dim base (32 dims)

  extern __shared__ float smem[];
  float* s_T = smem + L_ST;        // [j][256]
  float* s_sl = smem + L_SSL;      // [k][36]
  float* x_ch = smem + L_XCH;      // [4][16][20]
  float* p_ch = smem + L_PCH;      // [4][16][20]
  float* gi_sl = smem + L_GI;
  float* gh_sl = smem + L_GH;
  float* hc_sl = smem + L_HC;
  float* hp_sl = smem + L_HP;
  float* bih_sl = smem + L_BIH;
  float* bhh_sl = smem + L_BHH;
  float* d_sl = smem + L_D;

  const int wv = tid >> 6, lane = tid & 63;
  const int rowblk = tid >> 4, kseg = tid & 15;  // GEMM org: 32 rowblk x 16 kseg

  // ---- setup ----
  for (int e = tid; e < K_ * DPC; e += TPB) {
    int k = e >> 5, j = e & 31;
    float v = states[((size_t)k << 9) + d0 + j];
    s_T[j * 256 + k] = v;
    s_sl[k * 36 + j] = v;
  }
  if (tid < 96) {
    int grow = ((tid >> 5) << 9) + d0 + (tid & 31);
    bih_sl[tid] = bias_ih[grow];
    bhh_sl[tid] = bias_hh[grow];
  }
  if (tid < 128) {
    int b = tid >> 5, j = tid & 31;
    hp_sl[(b << 5) + j] = h0[((size_t)(g * NB + b) << 9) + d0 + j];
  }
  if (tid < 384) {
    int b = tid / 96, r = tid % 96;
    int grow = ((r >> 5) << 9) + d0 + (r & 31);
    gh_sl[b * 96 + r] = Gh0[(size_t)(g * NB + b) * G3H + grow];
  }
  // weight fragments -> registers: 3 rows x 16 k per thread, both matrices
  float4 wi[3][4], wh[3][4];
#pragma unroll
  for (int i = 0; i < 3; ++i) {
    int r = rowblk * 3 + i;  // 0..95
    int grow = ((r >> 5) << 9) + d0 + (r & 31);
    const float4* si = (const float4*)(W_ih + (size_t)grow * K_ + (kseg << 4));
    const float4* sh = (const float4*)(SWT + (size_t)grow * K_ + (kseg << 4));
    wi[i][0] = si[0]; wi[i][1] = si[1]; wi[i][2] = si[2]; wi[i][3] = si[3];
    wh[i][0] = sh[0]; wh[i][1] = sh[1]; wh[i][2] = sh[2]; wh[i][3] = sh[3];
  }
  __syncthreads();

  // ---- pre-loop: stage x(0) chunked, gi(0) ----
  if (tid < 256) {
    int b = tid >> 6, c = tid & 63;
    float4 v = *((const float4*)(input + ((size_t)(g * NB + b) * S_) * I_) + c);
    *(float4*)(x_ch + (b * 16 + (c >> 2)) * 20 + ((c & 3) << 2)) = v;
  }
  __syncthreads();
  {
    float acc[4][3] = {};
#pragma unroll
    for (int b = 0; b < 4; ++b) {
      const float4* xp = (const float4*)(x_ch + (b * 16 + kseg) * 20);
#pragma unroll
      for (int c = 0; c < 4; ++c) {
        float4 xv = xp[c];
#pragma unroll
        for (int i = 0; i < 3; ++i) acc[b][i] += dot4(wi[i][c], xv);
      }
    }
#pragma unroll
    for (int b = 0; b < 4; ++b)
#pragma unroll
      for (int i = 0; i < 3; ++i) {
        float v = acc[b][i];
        v += __shfl_xor(v, 1); v += __shfl_xor(v, 2);
        v += __shfl_xor(v, 4); v += __shfl_xor(v, 8);
        acc[b][i] = v;
      }
    if (kseg == 0) {
#pragma unroll
      for (int b = 0; b < 4; ++b)
#pragma unroll
        for (int i = 0; i < 3; ++i) gi_sl[b * 96 + rowblk * 3 + i] = acc[b][i];
    }
  }
  __syncthreads();

  for (int t = 0; t < S_; ++t) {
    const unsigned sb = (unsigned)((t >> 1) & 1) << 31;
    const unsigned long long expect =
        ((unsigned long long)sb << 32) | (unsigned long long)sb;
    unsigned long long* pks = pk + ((size_t)(t & 1) << 17);  // slot base

    // ---- A: gates + h_cand over owned 32 dims ----
    if (tid < 128) {
      int b = tid >> 5, j = tid & 31;
      float gir = gi_sl[b * 96 + j] + bih_sl[j];
      float giz = gi_sl[b * 96 + 32 + j] + bih_sl[32 + j];
      float gin = gi_sl[b * 96 + 64 + j] + bih_sl[64 + j];
      float ghr = gh_sl[b * 96 + j] + bhh_sl[j];
      float ghz = gh_sl[b * 96 + 32 + j] + bhh_sl[32 + j];
      float ghn = gh_sl[b * 96 + 64 + j] + bhh_sl[64 + j];
      float r = 1.f / (1.f + expf(-(gir + ghr)));
      float z = 1.f / (1.f + expf(-(giz + ghz)));
      float n = tanhf(gin + r * ghn);
      hc_sl[(b << 5) + j] = (1.f - z) * n + z * hp_sl[(b << 5) + j];
    }
    __syncthreads();

    // ---- B: dist partials (vectorized) -> packed sign-tagged stores ----
    {
      int b = tid >> 7;              // 0..3
      int sub = tid & 127;
      int k4 = sub >> 1;             // float4-of-k index 0..63
      int jh = sub & 1;              // j-half
      const float* hb = hc_sl + (b << 5) + (jh << 4);
      const float4* sp = (const float4*)(s_T + ((jh << 4) * 256) + (k4 << 2));
      float ax = 0.f, ay = 0.f, az = 0.f, aw = 0.f;
#pragma unroll
      for (int jj = 0; jj < 16; ++jj) {
        float4 s4 = sp[jj * 64];
        float hv = hb[jj];
        float e;
        e = hv - s4.x; ax += e * e;
        e = hv - s4.y; ay += e * e;
        e = hv - s4.z; az += e * e;
        e = hv - s4.w; aw += e * e;
      }
      ax += __shfl_xor(ax, 1);
      ay += __shfl_xor(ay, 1);
      az += __shfl_xor(az, 1);
      aw += __shfl_xor(aw, 1);
      if (jh == 0) {
        // word wp carries k = 2*wp (lo), 2*wp+1 (hi); wp = 2*k4, 2*k4+1
        unsigned long long* dst =
            pks + ((((size_t)(g * NB + b) * GCU) + cu) << 7) + (k4 << 1);
        tstore(dst + 0, pk_pack(ax, ay, sb));
        tstore(dst + 1, pk_pack(az, aw, sb));
      }
    }

    // ---- C (shadow): stage x(t+1) + gi(t+1) GEMM (register W_ih) ----
    if (t + 1 < S_) {
      if (tid < 256) {
        int b = tid >> 6, c = tid & 63;
        float4 v = *((const float4*)(input +
                     ((size_t)(g * NB + b) * S_ + (t + 1)) * I_) + c);
        *(float4*)(x_ch + (b * 16 + (c >> 2)) * 20 + ((c & 3) << 2)) = v;
      }
      __syncthreads();
      {
        float acc[4][3] = {};
#pragma unroll
        for (int b = 0; b < 4; ++b) {
          const float4* xp = (const float4*)(x_ch + (b * 16 + kseg) * 20);
#pragma unroll
          for (int c = 0; c < 4; ++c) {
            float4 xv = xp[c];
#pragma unroll
            for (int i = 0; i < 3; ++i) acc[b][i] += dot4(wi[i][c], xv);
          }
        }
#pragma unroll
        for (int b = 0; b < 4; ++b)
#pragma unroll
          for (int i = 0; i < 3; ++i) {
            float v = acc[b][i];
            v += __shfl_xor(v, 1); v += __shfl_xor(v, 2);
            v += __shfl_xor(v, 4); v += __shfl_xor(v, 8);
            acc[b][i] = v;
          }
        if (kseg == 0) {
#pragma unroll
          for (int b = 0; b < 4; ++b)
#pragma unroll
            for (int i = 0; i < 3; ++i)
              gi_sl[b * 96 + rowblk * 3 + i] = acc[b][i];
        }
      }
    }

    // ---- P: poll all 16 CUs' packed partials, reduce -> d_sl ----
    {
      int b = tid >> 7, kp = tid & 127;  // word index
      const unsigned long long* base =
          pks + (((size_t)(g * NB + b) * GCU) << 7) + kp;
      unsigned long long w[16];
#pragma unroll
      for (int s = 0; s < 16; ++s) w[s] = tload(base + (s << 7));
#pragma unroll
      for (int s = 0; s < 16; ++s) {
        int it = 0;
        while ((w[s] & SGNMASK) != expect && ++it < SPIN_MAX)
          w[s] = tload(base + (s << 7));
      }
      float dlo = 0.f, dhi = 0.f;
#pragma unroll
      for (int s = 0; s < 16; ++s) {
        dlo += __uint_as_float((unsigned)(w[s] & 0x7fffffffu));
        dhi += __uint_as_float((unsigned)((w[s] >> 32) & 0x7fffffffu));
      }
      d_sl[(b << 8) + (kp << 1) + 0] = dlo;
      d_sl[(b << 8) + (kp << 1) + 1] = dhi;
    }
    __syncthreads();

    // ---- G: softmax (waves 0-3, wave = batch) -> p_ch chunked + probs ----
    if (wv < NB) {
      int b = wv;
      const float* db = d_sl + (b << 8);
      float dd0 = db[lane], dd1 = db[lane + 64], dd2 = db[lane + 128],
            dd3 = db[lane + 192];
      float mn = fminf(fminf(dd0, dd1), fminf(dd2, dd3));
#pragma unroll
      for (int off = 32; off >= 1; off >>= 1) mn = fminf(mn, __shfl_xor(mn, off));
      float e0 = expf(mn - dd0), e1 = expf(mn - dd1), e2 = expf(mn - dd2),
            e3 = expf(mn - dd3);
      float s = (e0 + e1) + (e2 + e3);
#pragma unroll
      for (int off = 32; off >= 1; off >>= 1) s += __shfl_xor(s, off);
      float inv = 1.f / s;
      e0 *= inv; e1 *= inv; e2 *= inv; e3 *= inv;
      int hi = lane >> 4, lo = lane & 15;
      p_ch[(b * 16 + hi + 0) * 20 + lo] = e0;
      p_ch[(b * 16 + hi + 4) * 20 + lo] = e1;
      p_ch[(b * 16 + hi + 8) * 20 + lo] = e2;
      p_ch[(b * 16 + hi + 12) * 20 + lo] = e3;
      if (cu == 0) {
        float* pr = probs + (((size_t)(g * NB + b) * S_ + t) << 8);
        pr[lane] = e0; pr[lane + 64] = e1; pr[lane + 128] = e2;
        pr[lane + 192] = e3;
      }
    }
    __syncthreads();

    // ---- H1: gh(t+1) = p @ SWT^T from registers; p from chunked layout ----
    if (t + 1 < S_) {
      float acc[4][3] = {};
#pragma unroll
      for (int b = 0; b < 4; ++b) {
        const float4* xp = (const float4*)(p_ch + (b * 16 + kseg) * 20);
#pragma unroll
        for (int c = 0; c < 4; ++c) {
          float4 xv = xp[c];
#pragma unroll
          for (int i = 0; i < 3; ++i) acc[b][i] += dot4(wh[i][c], xv);
        }
      }
#pragma unroll
      for (int b = 0; b < 4; ++b)
#pragma unroll
        for (int i = 0; i < 3; ++i) {
          float v = acc[b][i];
          v += __shfl_xor(v, 1); v += __shfl_xor(v, 2);
          v += __shfl_xor(v, 4); v += __shfl_xor(v, 8);
          acc[b][i] = v;
        }
      if (kseg == 0) {
#pragma unroll
        for (int b = 0; b < 4; ++b)
#pragma unroll
          for (int i = 0; i < 3; ++i)
            gh_sl[b * 96 + rowblk * 3 + i] = acc[b][i];
      }
    }

    // ---- H2: h_new. thread = (b, j, kq) ----
    {
      int b = tid >> 7, j = (tid >> 2) & 31, kq = tid & 3;
      float a = 0.f;
#pragma unroll
      for (int i = 0; i < 16; ++i) {
        float4 p4 = *(const float4*)(p_ch + (b * 16 + i) * 20 + (kq << 2));
        int k = (i << 4) + (kq << 2);
        a += p4.x * s_sl[(k + 0) * 36 + j] + p4.y * s_sl[(k + 1) * 36 + j] +
             p4.z * s_sl[(k + 2) * 36 + j] + p4.w * s_sl[(k + 3) * 36 + j];
      }
      a += __shfl_xor(a, 1);
      a += __shfl_xor(a, 2);
      if (kq == 0) {
        hp_sl[(b << 5) + j] = a;
        out[(((size_t)(g * NB + b) * S_ + t) << 9) + d0 + j] = a;
      }
    }
    __syncthreads();
  }

  // ---- final hidden state ----
  if (tid < 128) {
    int b = tid >> 5, j = tid & 31;
    hn[((size_t)(g * NB + b) << 9) + d0 + j] = hp_sl[(b << 5) + j];
  }
}

// ---------------------------------------------------------------------------
extern "C" void kernel_launch(void* const* d_in, const int* in_sizes, int n_in,
                              void* d_out, int out_size, void* d_ws,
                              size_t ws_size, hipStream_t stream) {
  const float* input = (const float*)d_in[0];
  const float* h0 = (const float*)d_in[1];
  const float* W_ih = (const float*)d_in[2];
  const float* W_hh = (const float*)d_in[3];
  const float* bias_ih = (const float*)d_in[4];
  const float* bias_hh = (const float*)d_in[5];
  const float* states = (const float*)d_in[6];
  float* out = (float*)d_out;

  char* ws = (char*)d_ws;
  float* SWT = (float*)(ws + WS_SWT);
  float* Gh0 = (float*)(ws + WS_GH0);
  unsigned long long* pk = (unsigned long long*)(ws + WS_PK);

  // 0x80 bytes -> every packed float is negative -> never matches the
  // expected (non-stale) sign pattern at t=0/1; kills cross-replay staleness.
  (void)hipMemsetAsync(ws + WS_PK, 0x80, WS_PK_SZ, stream);
  kernel_swt<<<G3H / 8, 256, 0, stream>>>(W_hh, states, SWT);
  kernel_gh0<<<B_, 256, 0, stream>>>(W_hh, h0, Gh0);

  (void)hipFuncSetAttribute(reinterpret_cast<const void*>(srrnn_main),
                            hipFuncAttributeMaxDynamicSharedMemorySize,
                            SMEM_BYTES);
  srrnn_main<<<NGRP * GCU, TPB, SMEM_BYTES, stream>>>(
      input, h0, W_ih, bias_ih, bias_hh, states, SWT, Gh0, pk,
      out, out + OUT_OFF_HN, out + OUT_OFF_P);
}